// Round 10
// baseline (215.058 us; speedup 1.0000x reference)
//
#include <hip/hip_runtime.h>
#include <hip/hip_bf16.h>
#include <math.h>

#define NG 128
#define CHUNKB 2048
#define NBIN 512     // dst buckets of 256 nodes; >= ceil(N/256)
#define EWIN 256     // per-wave LDS edge window (16 nodes, mean 160, 5-sigma ~225)
#define STAGE_CAP 6144  // per-bucket LDS edge stage (mean 2560, +3.5sigma ~2740)

typedef __attribute__((ext_vector_type(8))) short short8;
typedef __attribute__((ext_vector_type(4))) float float4v;
typedef __attribute__((ext_vector_type(4))) uint uint4v;

// ---------- per-chunk bucket histogram -> GLOBAL bucket counts (atomics) ----------
// Exact per-(chunk,bucket) offsets are unnecessary: csrAB re-sorts within each
// bucket via per-node cursors, so bucket-internal order is free. This kills the
// hist array and both scan kernels. extra blocks: 0 -> pack W2, 1 -> pack W3.
__global__ void k_bin_hist(const int* __restrict__ dst, int* __restrict__ gcnt,
                           int e, int nb,
                           const float* __restrict__ W2, const float* __restrict__ W3,
                           __hip_bfloat16* __restrict__ Wf2, __hip_bfloat16* __restrict__ Wf3) {
    __shared__ int h[NBIN];
    int blk = blockIdx.x;
    if (blk >= nb) {
        int ex = blk - nb;
        const float* W = ex ? W3 : W2;
        __hip_bfloat16* Wf = ex ? Wf3 : Wf2;
        for (int t = threadIdx.x; t < 512; t += 256) {
            int c = t >> 6, l = t & 63;
            int jt = c >> 1, half = c & 1, nn = l & 15, q = l >> 4;
            #pragma unroll
            for (int j = 0; j < 8; j++) {
                int k = half * 32 + q * 8 + j;
                Wf[t * 8 + j] = __float2bfloat16(W[k * 64 + jt * 16 + nn]);
            }
        }
        return;
    }
    for (int i = threadIdx.x; i < NBIN; i += 256) h[i] = 0;
    __syncthreads();
    int base = blk * CHUNKB;
    int lim = e - base; if (lim > CHUNKB) lim = CHUNKB;
    for (int k = threadIdx.x; k < lim; k += 256)
        atomicAdd(&h[dst[base + k] >> 8], 1);
    __syncthreads();
    for (int b = threadIdx.x; b < NBIN; b += 256) {
        int v = h[b];
        if (v) atomicAdd(&gcnt[b], v);   // non-returning, 512 addresses
    }
}

// ---------- LDS-staged bucket scatter with per-run global reservation ----------
// Each block: local hist -> local scan -> clustered stage -> per-bucket
// atomicAdd(&gcur[b], cnt) reservation -> clustered write at gbase+res.
__global__ void k_bin_scatter(const int* __restrict__ srcs, const int* __restrict__ dsts,
                              const int* __restrict__ gcnt, int* __restrict__ gcur,
                              int* __restrict__ outbuf, int e, int nb) {
    __shared__ int hcnt[NBIN];     // local counts -> cursors
    __shared__ int lstart[NBIN];   // local start -> write delta
    __shared__ int ss[256];
    __shared__ int stage[CHUNKB];  // packed edges
    __shared__ int sbuck[CHUNKB];  // bucket id per staged slot
    int tid = threadIdx.x, blk = blockIdx.x, base = blk * CHUNKB;
    int lim = e - base; if (lim > CHUNKB) lim = CHUNKB;
    for (int i = tid; i < NBIN; i += 256) hcnt[i] = 0;
    __syncthreads();
    for (int k = tid; k < lim; k += 256)
        atomicAdd(&hcnt[dsts[base + k] >> 8], 1);
    __syncthreads();
    int c0 = hcnt[2 * tid], c1 = hcnt[2 * tid + 1];
    int sum = c0 + c1;
    ss[tid] = sum;
    __syncthreads();
    for (int d = 1; d < 256; d <<= 1) {
        int t = (tid >= d) ? ss[tid - d] : 0;
        __syncthreads();
        ss[tid] += t;
        __syncthreads();
    }
    int excl = ss[tid] - sum;
    lstart[2 * tid] = excl;
    lstart[2 * tid + 1] = excl + c0;
    __syncthreads();
    hcnt[2 * tid] = excl;          // cursors for staging
    hcnt[2 * tid + 1] = excl + c0;
    __syncthreads();
    for (int k = tid; k < lim; k += 256) {
        int s = srcs[base + k], d = dsts[base + k];
        int bk = d >> 8;
        int p = atomicAdd(&hcnt[bk], 1);
        stage[p] = ((d & 255) << 24) | s;
        sbuck[p] = bk;
    }
    __syncthreads();
    // exclusive scan of GLOBAL counts (512 ints) to get bucket bases
    int g0 = gcnt[2 * tid], g1 = gcnt[2 * tid + 1];
    int gs = g0 + g1;
    ss[tid] = gs;
    __syncthreads();
    for (int d = 1; d < 256; d <<= 1) {
        int t = (tid >= d) ? ss[tid - d] : 0;
        __syncthreads();
        ss[tid] += t;
        __syncthreads();
    }
    int gexcl = ss[tid] - gs;
    // reserve this chunk's run in each bucket; delta = final_base - local_start
    if (c0 > 0) {
        int r = atomicAdd(&gcur[2 * tid], c0);
        lstart[2 * tid] = gexcl + r - lstart[2 * tid];
    }
    if (c1 > 0) {
        int r = atomicAdd(&gcur[2 * tid + 1], c1);
        lstart[2 * tid + 1] = (gexcl + g0) + r - lstart[2 * tid + 1];
    }
    __syncthreads();
    for (int p = tid; p < lim; p += 256)
        outbuf[lstart[sbuck[p]] + p] = stage[p];
}

// ---------- block per bucket, FUSED: degree/row_ptr/dinv/x-prescale + CSR placement ----------
// Bucket bounds from an in-LDS scan of the 512 global counts (no offsets array).
__global__ void k_csrAB(const int* __restrict__ ebuck, const int* __restrict__ gcnt,
                        const float* __restrict__ x,
                        int* __restrict__ row_ptr, float* __restrict__ dinv,
                        float2* __restrict__ xs, int* __restrict__ csr,
                        int n, int e_total) {
    __shared__ int lcnt[256];
    __shared__ int ssc[256];
    __shared__ int rstart[256];
    __shared__ int exc[NBIN];
    __shared__ int stage[STAGE_CAP];
    int b = blockIdx.x, tid = threadIdx.x, n0 = b << 8;
    lcnt[tid] = 0;
    // exclusive scan of global bucket counts -> e0, e1
    int g0 = gcnt[2 * tid], g1 = gcnt[2 * tid + 1];
    int gs = g0 + g1;
    ssc[tid] = gs;
    __syncthreads();
    for (int d = 1; d < 256; d <<= 1) {
        int t = (tid >= d) ? ssc[tid - d] : 0;
        __syncthreads();
        ssc[tid] += t;
        __syncthreads();
    }
    int gexcl = ssc[tid] - gs;
    exc[2 * tid] = gexcl;
    exc[2 * tid + 1] = gexcl + g0;
    __syncthreads();
    int e0 = exc[b];
    int e1 = e0 + gcnt[b];
    int cnt = e1 - e0;
    bool fast = (cnt <= STAGE_CAP);
    if (fast) {
        for (int i = e0 + tid; i < e1; i += 256) {
            int p = ebuck[i];
            stage[i - e0] = p;
            atomicAdd(&lcnt[(uint)p >> 24], 1);
        }
    } else {
        for (int i = e0 + tid; i < e1; i += 256)
            atomicAdd(&lcnt[(uint)ebuck[i] >> 24], 1);
    }
    __syncthreads();
    int v = lcnt[tid];
    ssc[tid] = v;
    __syncthreads();
    for (int d = 1; d < 256; d <<= 1) {
        int t = (tid >= d) ? ssc[tid - d] : 0;
        __syncthreads();
        ssc[tid] += t;
        __syncthreads();
    }
    int rs = e0 + ssc[tid] - v;        // exclusive row start
    rstart[tid] = rs;
    int node = n0 + tid;
    if (node < n) {
        row_ptr[node] = rs;
        float dv = rsqrtf((float)v + 1.0f);
        dinv[node] = dv;
        const float2* x2 = (const float2*)x;
        float2 xi = x2[node];
        xs[node] = make_float2(xi.x * dv, xi.y * dv);   // prescaled x' = dinv * x
        if (node == n - 1) row_ptr[n] = e_total;
    }
    lcnt[tid] = 0;                     // reuse as placement cursors
    __syncthreads();
    if (fast) {
        for (int i = tid; i < cnt; i += 256) {
            int p = stage[i];
            int li = (uint)p >> 24;
            int r = atomicAdd(&lcnt[li], 1);
            csr[rstart[li] + r] = p & 0xFFFFFF;
        }
    } else {
        for (int i = e0 + tid; i < e1; i += 256) {
            int p = ebuck[i];
            int li = (uint)p >> 24;
            int r = atomicAdd(&lcnt[li], 1);
            csr[rstart[li] + r] = p & 0xFFFFFF;
        }
    }
}

// ---------- layer 1 fused: pull on prescaled x' (2 feats) + lin1 + relu -> h1' bf16 ----------
__global__ void k_layer1(const int* __restrict__ row_ptr, const int* __restrict__ edges,
                         const float2* __restrict__ xs, const float* __restrict__ dinv,
                         const float* __restrict__ W1, const float* __restrict__ b1,
                         __hip_bfloat16* __restrict__ h, int n) {
    __shared__ float w1s[128];
    __shared__ float b1s[64];
    if (threadIdx.x < 128) w1s[threadIdx.x] = W1[threadIdx.x];
    if (threadIdx.x < 64) b1s[threadIdx.x] = b1[threadIdx.x];
    __syncthreads();
    int i = blockIdx.x * blockDim.x + threadIdx.x;
    if (i >= n) return;
    float dd = dinv[i];
    float2 xi = xs[i];                 // self term: x'_d
    float a0 = xi.x, a1 = xi.y;
    int lo = row_ptr[i], hi = row_ptr[i + 1];
    int k = lo;
    for (; k + 4 <= hi; k += 4) {
        int s0 = edges[k], s1 = edges[k + 1], s2 = edges[k + 2], s3 = edges[k + 3];
        float2 v0 = xs[s0], v1 = xs[s1], v2 = xs[s2], v3 = xs[s3];
        a0 += v0.x + v1.x + v2.x + v3.x;
        a1 += v0.y + v1.y + v2.y + v3.y;
    }
    for (; k < hi; k++) {
        float2 v = xs[edges[k]];
        a0 += v.x;
        a1 += v.y;
    }
    a0 *= dd; a1 *= dd;                // conv output = dinv_d * (sum of prescaled)
    short8* hv = reinterpret_cast<short8*>(h + (size_t)i * 64);
    #pragma unroll
    for (int g = 0; g < 8; g++) {
        short8 pack;
        #pragma unroll
        for (int j = 0; j < 8; j++) {
            int col = g * 8 + j;
            float v = fmaxf(a0 * w1s[col] + a1 * w1s[64 + col] + b1s[col], 0.0f);
            v *= dd;                   // store h1' = dinv * h1 (prefold for next layer)
            __hip_bfloat16 bv = __float2bfloat16(v);
            pack[j] = *reinterpret_cast<short*>(&bv);
        }
        hv[g] = pack;
    }
}

// ---------- accumulate 8 bf16 (one uint4v) into 8 f32 ----------
static __device__ __forceinline__ void acc8(float* a, uint4v v) {
    #pragma unroll
    for (int i = 0; i < 4; i++) {
        uint u = v[i];
        a[2 * i]     += __int_as_float(u << 16);
        a[2 * i + 1] += __int_as_float(u & 0xffff0000u);
    }
}

// ---------- 8-lane-per-node gather core (unroll-2, R6-proven; always-valid address,
// ---------- data zeroed in register; unroll-4 measured +3us = revert) ----------
template <bool FAST>
static __device__ __forceinline__ void agg_group(int lo, int cnt, int mc, int c,
        const int* __restrict__ gE, const int* EW, int wave_lo,
        const uint4v* __restrict__ hin4, float* acc) {
    for (int j = 0; j < mc; j += 2) {
        bool ok0 = j < cnt, ok1 = j + 1 < cnt;
        int e0 = ok0 ? lo + j : wave_lo;       // clamp to a guaranteed-valid edge
        int e1 = ok1 ? lo + j + 1 : wave_lo;
        int s0 = FAST ? EW[e0 - wave_lo] : gE[e0];
        int s1 = FAST ? EW[e1 - wave_lo] : gE[e1];
        uint4v v0 = hin4[(size_t)s0 * 8 + c];
        uint4v v1 = hin4[(size_t)s1 * 8 + c];
        if (!ok0) v0 = (uint4v){0u, 0u, 0u, 0u};
        if (!ok1) v1 = (uint4v){0u, 0u, 0u, 0u};
        acc8(acc, v0);
        acc8(acc, v1);
    }
}

// ---------- fused agg + MFMA linear (+ optional fused mean-pool) ----------
// ONE wave per block ((64,8): tiny LDS, max WG/CU residency for gather-latency
// hiding -- R3's 4-wave and R8's phasing both regressed; R5: no fused head).
// Input h is PRESCALED (h' = dinv*h).
template <int RELU, int POOL>
__global__ void __launch_bounds__(64, 8) k_aggLin(const int* __restrict__ row_ptr,
                                                  const int* __restrict__ edges,
                                                  const __hip_bfloat16* __restrict__ hin,
                                                  const float* __restrict__ dinv,
                                                  const __hip_bfloat16* __restrict__ Wf,
                                                  const float* __restrict__ b,
                                                  __hip_bfloat16* __restrict__ hout,
                                                  const int* __restrict__ batch,
                                                  float* __restrict__ sums, int n) {
    __shared__ __attribute__((aligned(16))) __hip_bfloat16 T[16 * 72];
    __shared__ int EW[EWIN];
    int lane = threadIdx.x;
    int nb0 = blockIdx.x * 16;
    if (nb0 >= n) return;
    int g = lane >> 3;                 // node within group of 8
    int c = lane & 7;                  // dwordx4 slice within row (8 bf16 cols)
    const uint4v* hin4 = reinterpret_cast<const uint4v*>(hin);

    // lanes 0..16 hold the 17 row_ptr boundaries for this wave's nodes
    int bidx = nb0 + (lane < 16 ? lane : 16);
    if (bidx > n) bidx = n;
    int rp = row_ptr[bidx];
    int wave_lo = __shfl(rp, 0);
    int wave_hi = __shfl(rp, 16);
    int cnt_all = wave_hi - wave_lo;
    bool fast = (cnt_all <= EWIN);
    if (fast)
        for (int i = lane; i < cnt_all; i += 64) EW[i] = edges[wave_lo + i];
    // same-wave LDS write->read ordering (in-order LDS pipe)

    #pragma unroll
    for (int h8 = 0; h8 < 2; h8++) {
        int nn = h8 * 8 + g;
        int node = nb0 + nn;
        float acc[8] = {0.f, 0.f, 0.f, 0.f, 0.f, 0.f, 0.f, 0.f};
        int lo = __shfl(rp, nn);
        int hi = __shfl(rp, nn + 1);
        int cnt = (node < n) ? (hi - lo) : 0;
        int mc = cnt;                              // wave-uniform max over the 8 octs
        mc = max(mc, __shfl_xor(mc, 8));
        mc = max(mc, __shfl_xor(mc, 16));
        mc = max(mc, __shfl_xor(mc, 32));
        if (node < n)
            acc8(acc, hin4[(size_t)node * 8 + c]); // self term h'[d]
        if (fast) agg_group<true >(lo, cnt, mc, c, edges, EW, wave_lo, hin4, acc);
        else      agg_group<false>(lo, cnt, mc, c, edges, EW, wave_lo, hin4, acc);
        float dv = (node < n) ? dinv[node] : 0.0f;
        uint4v pk;
        #pragma unroll
        for (int i = 0; i < 4; i++) {
            __hip_bfloat16 bx = __float2bfloat16(acc[2 * i] * dv);
            __hip_bfloat16 by = __float2bfloat16(acc[2 * i + 1] * dv);
            pk[i] = (uint)(*reinterpret_cast<unsigned short*>(&bx)) |
                    ((uint)(*reinterpret_cast<unsigned short*>(&by)) << 16);
        }
        *reinterpret_cast<uint4v*>(&T[nn * 72 + c * 8]) = pk;
    }

    // MFMA phase on the wave's 16x64 tile
    int m = lane & 15, q = lane >> 4;
    short8 a0 = *reinterpret_cast<const short8*>(&T[m * 72 + q * 8]);
    short8 a1 = *reinterpret_cast<const short8*>(&T[m * 72 + 32 + q * 8]);
    int lastn = nb0 + 15 < n ? nb0 + 15 : n - 1;
    bool onegraph = POOL && (nb0 + 15 < n) && (batch[nb0] == batch[lastn]);
    int gA = POOL ? batch[nb0] : 0;
    float dvs[4];
    if (!POOL) {
        #pragma unroll
        for (int r = 0; r < 4; r++) {
            int node = nb0 + q * 4 + r;
            dvs[r] = node < n ? dinv[node] : 0.0f;
        }
    }
    #pragma unroll
    for (int jt = 0; jt < 4; jt++) {
        short8 bf0 = *reinterpret_cast<const short8*>(Wf + ((size_t)(jt * 2 + 0) * 64 + lane) * 8);
        short8 bf1 = *reinterpret_cast<const short8*>(Wf + ((size_t)(jt * 2 + 1) * 64 + lane) * 8);
        float4v d = {0.0f, 0.0f, 0.0f, 0.0f};
        d = __builtin_amdgcn_mfma_f32_16x16x32_bf16(a0, bf0, d, 0, 0, 0);
        d = __builtin_amdgcn_mfma_f32_16x16x32_bf16(a1, bf1, d, 0, 0, 0);
        float bias = b[jt * 16 + m];           // C/D col = lane&15
        if (POOL) {
            if (onegraph) {
                float s = (d[0] + bias) + (d[1] + bias) + (d[2] + bias) + (d[3] + bias);
                s += __shfl_xor(s, 16);
                s += __shfl_xor(s, 32);
                if (q == 0) atomicAdd(&sums[gA * 64 + jt * 16 + m], s);
            } else {
                #pragma unroll
                for (int r = 0; r < 4; r++) {
                    int node = nb0 + q * 4 + r;
                    if (node < n)
                        atomicAdd(&sums[batch[node] * 64 + jt * 16 + m], d[r] + bias);
                }
            }
        } else {
            #pragma unroll
            for (int r = 0; r < 4; r++) {
                int node = nb0 + q * 4 + r;    // C/D row = quad*4 + reg
                if (node < n) {
                    float v = d[r] + bias;
                    if (RELU) v = fmaxf(v, 0.0f);
                    v *= dvs[r];               // store prescaled h' for next layer
                    hout[(size_t)node * 64 + jt * 16 + m] = __float2bfloat16(v);
                }
            }
        }
    }
}

// ---------- head (counts via binary search on sorted batch) ----------
__device__ inline int lower_bound_i(const int* __restrict__ a, int n, int key) {
    int lo = 0, hi = n;
    while (lo < hi) {
        int mid = (lo + hi) >> 1;
        if (a[mid] < key) lo = mid + 1; else hi = mid;
    }
    return lo;
}

__global__ void k_head(const float* __restrict__ sums, const int* __restrict__ batch,
                       const float* __restrict__ ge, const float* __restrict__ Wl,
                       const float* __restrict__ bl, float* __restrict__ out,
                       int n, int ng) {
    int g = blockIdx.x * blockDim.x + threadIdx.x;
    if (g < ng) {
        int lo = lower_bound_i(batch, n, g);
        int hi = lower_bound_i(batch, n, g + 1);
        float c = fmaxf((float)(hi - lo), 1.0f);
        float z[5];
        for (int cl = 0; cl < 5; cl++) z[cl] = bl[cl];
        for (int k = 0; k < 64; k++) {
            float p = sums[g * 64 + k] / c;
            for (int cl = 0; cl < 5; cl++) z[cl] += p * Wl[k * 5 + cl];
        }
        for (int k = 0; k < 64; k++) {
            float p = ge[g * 64 + k];
            for (int cl = 0; cl < 5; cl++) z[cl] += p * Wl[(64 + k) * 5 + cl];
        }
        float m = z[0];
        for (int cl = 1; cl < 5; cl++) m = fmaxf(m, z[cl]);
        float s = 0.0f;
        for (int cl = 0; cl < 5; cl++) s += expf(z[cl] - m);
        float lse = m + logf(s);
        for (int cl = 0; cl < 5; cl++) out[g * 5 + cl] = z[cl] - lse;
    }
}

#define ALIGN16(x) (((x) + 15) & ~(size_t)15)

extern "C" void kernel_launch(void* const* d_in, const int* in_sizes, int n_in,
                              void* d_out, int out_size, void* d_ws, size_t ws_size,
                              hipStream_t stream) {
    const float* x    = (const float*)d_in[0];
    const int*   ei   = (const int*)d_in[1];
    const int*   batch= (const int*)d_in[2];
    const float* ge   = (const float*)d_in[3];
    const float* W1   = (const float*)d_in[4];
    const float* b1   = (const float*)d_in[5];
    const float* W2   = (const float*)d_in[6];
    const float* b2   = (const float*)d_in[7];
    const float* W3   = (const float*)d_in[8];
    const float* b3   = (const float*)d_in[9];
    const float* Wl   = (const float*)d_in[10];
    const float* bl   = (const float*)d_in[11];
    float* out = (float*)d_out;

    const int N = in_sizes[0] / 2;   // x is [N,2]
    const int E = in_sizes[1] / 2;   // edge_index is [2,E]
    const int* src = ei;
    const int* dst = ei + E;
    const int NBUK = (N + 255) >> 8;             // actual dst buckets (<= NBIN)
    const int nbC  = (E + CHUNKB - 1) / CHUNKB;  // sort chunks

    // ---- workspace layout (segments 16B-aligned; sums/gcnt/gcur contiguous for one memset) ----
    char* wsb = (char*)d_ws;
    float* dinv   = (float*)wsb;                wsb += ALIGN16((size_t)N * 4);
    float2* xs    = (float2*)wsb;               wsb += ALIGN16((size_t)N * 8);   // x' = dinv*x
    __hip_bfloat16* h16 = (__hip_bfloat16*)wsb;  wsb += ALIGN16((size_t)64 * N * 2);  // h1'
    __hip_bfloat16* buf2= (__hip_bfloat16*)wsb;  wsb += ALIGN16((size_t)64 * N * 2);  // h2'
    float* sums   = (float*)wsb;                wsb += ALIGN16((size_t)NG * 64 * 4);
    int*   gcnt   = (int*)wsb;                  wsb += ALIGN16((size_t)NBIN * 4);
    int*   gcur   = (int*)wsb;                  wsb += ALIGN16((size_t)NBIN * 4);
    __hip_bfloat16* Wf2 = (__hip_bfloat16*)wsb; wsb += ALIGN16((size_t)4096 * 2);
    __hip_bfloat16* Wf3 = (__hip_bfloat16*)wsb; wsb += ALIGN16((size_t)4096 * 2);
    int*   ebuck  = (int*)wsb;                  wsb += ALIGN16((size_t)E * 4);   // packed (ldst<<24|src)
    int*   csr    = (int*)wsb;                  wsb += ALIGN16((size_t)E * 4);   // src only
    int*   row_ptr= (int*)wsb;                  wsb += ALIGN16((size_t)(N + 1) * 4);

    const int BS = 256;
    int gN   = (N + BS - 1) / BS;
    int gF   = (N + 15) / 16;                    // k_aggLin: 1 wave (16 nodes) per block

    // ---- CSR build: global-count bucket sort (no scan kernels, no hist array) ----
    hipMemsetAsync(sums, 0, (size_t)NG * 64 * 4 + 2 * ALIGN16((size_t)NBIN * 4), stream);
    k_bin_hist<<<nbC + 2, BS, 0, stream>>>(dst, gcnt, E, nbC, W2, W3, Wf2, Wf3);
    k_bin_scatter<<<nbC, BS, 0, stream>>>(src, dst, gcnt, gcur, ebuck, E, nbC);
    k_csrAB<<<NBUK, BS, 0, stream>>>(ebuck, gcnt, x, row_ptr, dinv, xs, csr, N, E);

    // ---- layer 1: fused pull on x' + lin1 + relu -> h1' (h16) ----
    k_layer1<<<gN, BS, 0, stream>>>(row_ptr, csr, xs, dinv, W1, b1, h16, N);

    // ---- layer 2: fused agg(h1') + lin2 + relu -> h2' (buf2) ----
    k_aggLin<1, 0><<<gF, 64, 0, stream>>>(row_ptr, csr, h16, dinv, Wf2, b2, buf2,
                                          nullptr, nullptr, N);

    // ---- layer 3: fused agg(h2') + lin3 + mean-pool -> sums (no h3 buffer) ----
    k_aggLin<0, 1><<<gF, 64, 0, stream>>>(row_ptr, csr, buf2, dinv, Wf3, b3, nullptr,
                                          batch, sums, N);

    // ---- head ----
    k_head<<<1, 128, 0, stream>>>(sums, batch, ge, Wl, bl, out, N, NG);
}

// Round 11
// 195.336 us; speedup vs baseline: 1.1010x; 1.1010x over previous
//
#include <hip/hip_runtime.h>
#include <hip/hip_bf16.h>
#include <math.h>

#define NG 128
#define CHUNKB 2048
#define NBIN 512     // dst buckets of 256 nodes; >= ceil(N/256)
#define EWIN 256     // per-wave LDS edge window (16 nodes, mean 160, 5-sigma ~225)
#define STAGE_CAP 6144  // per-bucket LDS edge stage (mean 2560, +3.5sigma ~2740)

typedef __attribute__((ext_vector_type(8))) short short8;
typedef __attribute__((ext_vector_type(4))) float float4v;
typedef __attribute__((ext_vector_type(4))) uint uint4v;

// ---------- per-chunk bucket histogram (LDS only) + fused init work ----------
// extra blocks (blockIdx >= nb): 0 -> zero sums, 1 -> pack W2, 2 -> pack W3.
// NOTE (R10 lesson): the hist+scan chain beats a global-atomic-count build by
// ~20us -- bulk coalesced traffic is cheaper than coherence-point RMW latency.
__global__ void k_bin_hist(const int* __restrict__ dst, int* __restrict__ hist,
                           int e, int nb, float* __restrict__ sums,
                           const float* __restrict__ W2, const float* __restrict__ W3,
                           __hip_bfloat16* __restrict__ Wf2, __hip_bfloat16* __restrict__ Wf3) {
    __shared__ int h[NBIN];
    int blk = blockIdx.x;
    if (blk >= nb) {
        int ex = blk - nb;
        if (ex == 0) {
            for (int i = threadIdx.x; i < NG * 64; i += 256) sums[i] = 0.0f;
        } else {
            const float* W = (ex == 2) ? W3 : W2;
            __hip_bfloat16* Wf = (ex == 2) ? Wf3 : Wf2;
            for (int t = threadIdx.x; t < 512; t += 256) {
                int c = t >> 6, l = t & 63;
                int jt = c >> 1, half = c & 1, nn = l & 15, q = l >> 4;
                #pragma unroll
                for (int j = 0; j < 8; j++) {
                    int k = half * 32 + q * 8 + j;
                    Wf[t * 8 + j] = __float2bfloat16(W[k * 64 + jt * 16 + nn]);
                }
            }
        }
        return;
    }
    for (int i = threadIdx.x; i < NBIN; i += 256) h[i] = 0;
    __syncthreads();
    int base = blk * CHUNKB;
    int lim = e - base; if (lim > CHUNKB) lim = CHUNKB;
    for (int k = threadIdx.x; k < lim; k += 256)
        atomicAdd(&h[dst[base + k] >> 8], 1);
    __syncthreads();
    for (int b = threadIdx.x; b < NBIN; b += 256) hist[b * nb + blk] = h[b];
}

// ---------- generic exclusive scan (512-thread blocks) ----------
__global__ void __launch_bounds__(512) genscan1(int* __restrict__ a, int* __restrict__ bsums, int n) {
    __shared__ int s[512];
    int tid = threadIdx.x;
    int i = blockIdx.x * 512 + tid;
    int v = (i < n) ? a[i] : 0;
    s[tid] = v;
    __syncthreads();
    for (int d = 1; d < 512; d <<= 1) {
        int t = (tid >= d) ? s[tid - d] : 0;
        __syncthreads();
        s[tid] += t;
        __syncthreads();
    }
    if (i < n) a[i] = s[tid] - v;   // exclusive, in place
    if (tid == 511) bsums[blockIdx.x] = s[511];
}

__global__ void __launch_bounds__(512) genscan2(int* __restrict__ bsums, int nb) {
    __shared__ int s[512];
    int tid = threadIdx.x;
    int v = (tid < nb) ? bsums[tid] : 0;
    s[tid] = v;
    __syncthreads();
    for (int d = 1; d < 512; d <<= 1) {
        int t = (tid >= d) ? s[tid - d] : 0;
        __syncthreads();
        s[tid] += t;
        __syncthreads();
    }
    if (tid < nb) bsums[tid] = s[tid] - v;
}
// offset(i) = hist[i] + bsums[i >> 9], fused into consumers

// ---------- LDS-staged bucket scatter; output packed (ldst<<24 | src) ----------
__global__ void k_bin_scatter(const int* __restrict__ srcs, const int* __restrict__ dsts,
                              const int* __restrict__ offsets, const int* __restrict__ bsums,
                              int* __restrict__ outbuf, int e, int nb) {
    __shared__ int hcnt[NBIN];     // counts -> cursor
    __shared__ int lstart[NBIN];   // local start -> delta
    __shared__ int ss[256];
    __shared__ int stage[CHUNKB];  // packed edges
    __shared__ int sbuck[CHUNKB];  // bucket id per staged slot
    int tid = threadIdx.x, blk = blockIdx.x, base = blk * CHUNKB;
    int lim = e - base; if (lim > CHUNKB) lim = CHUNKB;
    for (int i = tid; i < NBIN; i += 256) hcnt[i] = 0;
    __syncthreads();
    for (int k = tid; k < lim; k += 256)
        atomicAdd(&hcnt[dsts[base + k] >> 8], 1);
    __syncthreads();
    int c0 = hcnt[2 * tid], c1 = hcnt[2 * tid + 1];
    int sum = c0 + c1;
    ss[tid] = sum;
    __syncthreads();
    for (int d = 1; d < 256; d <<= 1) {
        int t = (tid >= d) ? ss[tid - d] : 0;
        __syncthreads();
        ss[tid] += t;
        __syncthreads();
    }
    int excl = ss[tid] - sum;
    lstart[2 * tid] = excl;
    lstart[2 * tid + 1] = excl + c0;
    __syncthreads();
    hcnt[2 * tid] = excl;          // cursors
    hcnt[2 * tid + 1] = excl + c0;
    __syncthreads();
    for (int k = tid; k < lim; k += 256) {
        int s = srcs[base + k], d = dsts[base + k];
        int bk = d >> 8;
        int p = atomicAdd(&hcnt[bk], 1);
        stage[p] = ((d & 255) << 24) | s;
        sbuck[p] = bk;
    }
    __syncthreads();
    for (int i = tid; i < NBIN; i += 256) {
        int gi = i * nb + blk;
        lstart[i] = offsets[gi] + bsums[gi >> 9] - lstart[i];
    }
    __syncthreads();
    for (int p = tid; p < lim; p += 256)
        outbuf[lstart[sbuck[p]] + p] = stage[p];
}

// ---------- block per bucket, FUSED: degree/row_ptr/dinv/x-prescale + CSR placement ----------
__global__ void k_csrAB(const int* __restrict__ ebuck, const int* __restrict__ offsets,
                        const int* __restrict__ bsums, const float* __restrict__ x,
                        int* __restrict__ row_ptr, float* __restrict__ dinv,
                        float2* __restrict__ xs, int* __restrict__ csr,
                        int n, int nb, int e_total) {
    __shared__ int lcnt[256];
    __shared__ int ssc[256];
    __shared__ int rstart[256];
    __shared__ int stage[STAGE_CAP];
    int b = blockIdx.x, tid = threadIdx.x, n0 = b << 8;
    lcnt[tid] = 0;
    __syncthreads();
    int i0 = b * nb, i1 = (b + 1) * nb;
    int e0 = offsets[i0] + bsums[i0 >> 9];
    int e1 = offsets[i1] + bsums[i1 >> 9];
    int cnt = e1 - e0;
    bool fast = (cnt <= STAGE_CAP);
    if (fast) {
        for (int i = e0 + tid; i < e1; i += 256) {
            int p = ebuck[i];
            stage[i - e0] = p;
            atomicAdd(&lcnt[(uint)p >> 24], 1);
        }
    } else {
        for (int i = e0 + tid; i < e1; i += 256)
            atomicAdd(&lcnt[(uint)ebuck[i] >> 24], 1);
    }
    __syncthreads();
    int v = lcnt[tid];
    ssc[tid] = v;
    __syncthreads();
    for (int d = 1; d < 256; d <<= 1) {
        int t = (tid >= d) ? ssc[tid - d] : 0;
        __syncthreads();
        ssc[tid] += t;
        __syncthreads();
    }
    int rs = e0 + ssc[tid] - v;        // exclusive row start
    rstart[tid] = rs;
    int node = n0 + tid;
    if (node < n) {
        row_ptr[node] = rs;
        float dv = rsqrtf((float)v + 1.0f);
        dinv[node] = dv;
        const float2* x2 = (const float2*)x;
        float2 xi = x2[node];
        xs[node] = make_float2(xi.x * dv, xi.y * dv);   // prescaled x' = dinv * x
        if (node == n - 1) row_ptr[n] = e_total;
    }
    lcnt[tid] = 0;                     // reuse as placement cursors
    __syncthreads();
    if (fast) {
        for (int i = tid; i < cnt; i += 256) {
            int p = stage[i];
            int li = (uint)p >> 24;
            int r = atomicAdd(&lcnt[li], 1);
            csr[rstart[li] + r] = p & 0xFFFFFF;
        }
    } else {
        for (int i = e0 + tid; i < e1; i += 256) {
            int p = ebuck[i];
            int li = (uint)p >> 24;
            int r = atomicAdd(&lcnt[li], 1);
            csr[rstart[li] + r] = p & 0xFFFFFF;
        }
    }
}

// ---------- layer 1 fused: pull on prescaled x' (2 feats) + lin1 + relu -> h1' bf16 ----------
__global__ void k_layer1(const int* __restrict__ row_ptr, const int* __restrict__ edges,
                         const float2* __restrict__ xs, const float* __restrict__ dinv,
                         const float* __restrict__ W1, const float* __restrict__ b1,
                         __hip_bfloat16* __restrict__ h, int n) {
    __shared__ float w1s[128];
    __shared__ float b1s[64];
    if (threadIdx.x < 128) w1s[threadIdx.x] = W1[threadIdx.x];
    if (threadIdx.x < 64) b1s[threadIdx.x] = b1[threadIdx.x];
    __syncthreads();
    int i = blockIdx.x * blockDim.x + threadIdx.x;
    if (i >= n) return;
    float dd = dinv[i];
    float2 xi = xs[i];                 // self term: x'_d
    float a0 = xi.x, a1 = xi.y;
    int lo = row_ptr[i], hi = row_ptr[i + 1];
    int k = lo;
    for (; k + 4 <= hi; k += 4) {
        int s0 = edges[k], s1 = edges[k + 1], s2 = edges[k + 2], s3 = edges[k + 3];
        float2 v0 = xs[s0], v1 = xs[s1], v2 = xs[s2], v3 = xs[s3];
        a0 += v0.x + v1.x + v2.x + v3.x;
        a1 += v0.y + v1.y + v2.y + v3.y;
    }
    for (; k < hi; k++) {
        float2 v = xs[edges[k]];
        a0 += v.x;
        a1 += v.y;
    }
    a0 *= dd; a1 *= dd;                // conv output = dinv_d * (sum of prescaled)
    short8* hv = reinterpret_cast<short8*>(h + (size_t)i * 64);
    #pragma unroll
    for (int g = 0; g < 8; g++) {
        short8 pack;
        #pragma unroll
        for (int j = 0; j < 8; j++) {
            int col = g * 8 + j;
            float v = fmaxf(a0 * w1s[col] + a1 * w1s[64 + col] + b1s[col], 0.0f);
            v *= dd;                   // store h1' = dinv * h1 (prefold for next layer)
            __hip_bfloat16 bv = __float2bfloat16(v);
            pack[j] = *reinterpret_cast<short*>(&bv);
        }
        hv[g] = pack;
    }
}

// ---------- accumulate 8 bf16 (one uint4v) into 8 f32 ----------
static __device__ __forceinline__ void acc8(float* a, uint4v v) {
    #pragma unroll
    for (int i = 0; i < 4; i++) {
        uint u = v[i];
        a[2 * i]     += __int_as_float(u << 16);
        a[2 * i + 1] += __int_as_float(u & 0xffff0000u);
    }
}

// ---------- 8-lane-per-node gather core (unroll-2, best-measured; always-valid
// ---------- address, data zeroed in register; unroll-4 measured +3us) ----------
template <bool FAST>
static __device__ __forceinline__ void agg_group(int lo, int cnt, int mc, int c,
        const int* __restrict__ gE, const int* EW, int wave_lo,
        const uint4v* __restrict__ hin4, float* acc) {
    for (int j = 0; j < mc; j += 2) {
        bool ok0 = j < cnt, ok1 = j + 1 < cnt;
        int e0 = ok0 ? lo + j : wave_lo;       // clamp to a guaranteed-valid edge
        int e1 = ok1 ? lo + j + 1 : wave_lo;
        int s0 = FAST ? EW[e0 - wave_lo] : gE[e0];
        int s1 = FAST ? EW[e1 - wave_lo] : gE[e1];
        uint4v v0 = hin4[(size_t)s0 * 8 + c];
        uint4v v1 = hin4[(size_t)s1 * 8 + c];
        if (!ok0) v0 = (uint4v){0u, 0u, 0u, 0u};
        if (!ok1) v1 = (uint4v){0u, 0u, 0u, 0u};
        acc8(acc, v0);
        acc8(acc, v1);
    }
}

// ---------- fused agg + MFMA linear (+ optional fused mean-pool) ----------
// ONE wave per block ((64,8): tiny LDS, max WG/CU residency for gather-latency
// hiding). Measured dead ends: 4-wave blocks (R3, -100us), fused head ticket
// (R5, -80us), agent fence (R4, -57us), unroll-4 (R7, -3us), src-phasing
// (R8, -10us), atomic CSR build (R10, -20us). Input h is PRESCALED (h'=dinv*h).
template <int RELU, int POOL>
__global__ void __launch_bounds__(64, 8) k_aggLin(const int* __restrict__ row_ptr,
                                                  const int* __restrict__ edges,
                                                  const __hip_bfloat16* __restrict__ hin,
                                                  const float* __restrict__ dinv,
                                                  const __hip_bfloat16* __restrict__ Wf,
                                                  const float* __restrict__ b,
                                                  __hip_bfloat16* __restrict__ hout,
                                                  const int* __restrict__ batch,
                                                  float* __restrict__ sums, int n) {
    __shared__ __attribute__((aligned(16))) __hip_bfloat16 T[16 * 72];
    __shared__ int EW[EWIN];
    int lane = threadIdx.x;
    int nb0 = blockIdx.x * 16;
    if (nb0 >= n) return;
    int g = lane >> 3;                 // node within group of 8
    int c = lane & 7;                  // dwordx4 slice within row (8 bf16 cols)
    const uint4v* hin4 = reinterpret_cast<const uint4v*>(hin);

    // lanes 0..16 hold the 17 row_ptr boundaries for this wave's nodes
    int bidx = nb0 + (lane < 16 ? lane : 16);
    if (bidx > n) bidx = n;
    int rp = row_ptr[bidx];
    int wave_lo = __shfl(rp, 0);
    int wave_hi = __shfl(rp, 16);
    int cnt_all = wave_hi - wave_lo;
    bool fast = (cnt_all <= EWIN);
    if (fast)
        for (int i = lane; i < cnt_all; i += 64) EW[i] = edges[wave_lo + i];
    // same-wave LDS write->read ordering (in-order LDS pipe)

    #pragma unroll
    for (int h8 = 0; h8 < 2; h8++) {
        int nn = h8 * 8 + g;
        int node = nb0 + nn;
        float acc[8] = {0.f, 0.f, 0.f, 0.f, 0.f, 0.f, 0.f, 0.f};
        int lo = __shfl(rp, nn);
        int hi = __shfl(rp, nn + 1);
        int cnt = (node < n) ? (hi - lo) : 0;
        int mc = cnt;                              // wave-uniform max over the 8 octs
        mc = max(mc, __shfl_xor(mc, 8));
        mc = max(mc, __shfl_xor(mc, 16));
        mc = max(mc, __shfl_xor(mc, 32));
        if (node < n)
            acc8(acc, hin4[(size_t)node * 8 + c]); // self term h'[d]
        if (fast) agg_group<true >(lo, cnt, mc, c, edges, EW, wave_lo, hin4, acc);
        else      agg_group<false>(lo, cnt, mc, c, edges, EW, wave_lo, hin4, acc);
        float dv = (node < n) ? dinv[node] : 0.0f;
        uint4v pk;
        #pragma unroll
        for (int i = 0; i < 4; i++) {
            __hip_bfloat16 bx = __float2bfloat16(acc[2 * i] * dv);
            __hip_bfloat16 by = __float2bfloat16(acc[2 * i + 1] * dv);
            pk[i] = (uint)(*reinterpret_cast<unsigned short*>(&bx)) |
                    ((uint)(*reinterpret_cast<unsigned short*>(&by)) << 16);
        }
        *reinterpret_cast<uint4v*>(&T[nn * 72 + c * 8]) = pk;
    }

    // MFMA phase on the wave's 16x64 tile
    int m = lane & 15, q = lane >> 4;
    short8 a0 = *reinterpret_cast<const short8*>(&T[m * 72 + q * 8]);
    short8 a1 = *reinterpret_cast<const short8*>(&T[m * 72 + 32 + q * 8]);
    int lastn = nb0 + 15 < n ? nb0 + 15 : n - 1;
    bool onegraph = POOL && (nb0 + 15 < n) && (batch[nb0] == batch[lastn]);
    int gA = POOL ? batch[nb0] : 0;
    float dvs[4];
    if (!POOL) {
        #pragma unroll
        for (int r = 0; r < 4; r++) {
            int node = nb0 + q * 4 + r;
            dvs[r] = node < n ? dinv[node] : 0.0f;
        }
    }
    #pragma unroll
    for (int jt = 0; jt < 4; jt++) {
        short8 bf0 = *reinterpret_cast<const short8*>(Wf + ((size_t)(jt * 2 + 0) * 64 + lane) * 8);
        short8 bf1 = *reinterpret_cast<const short8*>(Wf + ((size_t)(jt * 2 + 1) * 64 + lane) * 8);
        float4v d = {0.0f, 0.0f, 0.0f, 0.0f};
        d = __builtin_amdgcn_mfma_f32_16x16x32_bf16(a0, bf0, d, 0, 0, 0);
        d = __builtin_amdgcn_mfma_f32_16x16x32_bf16(a1, bf1, d, 0, 0, 0);
        float bias = b[jt * 16 + m];           // C/D col = lane&15
        if (POOL) {
            if (onegraph) {
                float s = (d[0] + bias) + (d[1] + bias) + (d[2] + bias) + (d[3] + bias);
                s += __shfl_xor(s, 16);
                s += __shfl_xor(s, 32);
                if (q == 0) atomicAdd(&sums[gA * 64 + jt * 16 + m], s);
            } else {
                #pragma unroll
                for (int r = 0; r < 4; r++) {
                    int node = nb0 + q * 4 + r;
                    if (node < n)
                        atomicAdd(&sums[batch[node] * 64 + jt * 16 + m], d[r] + bias);
                }
            }
        } else {
            #pragma unroll
            for (int r = 0; r < 4; r++) {
                int node = nb0 + q * 4 + r;    // C/D row = quad*4 + reg
                if (node < n) {
                    float v = d[r] + bias;
                    if (RELU) v = fmaxf(v, 0.0f);
                    v *= dvs[r];               // store prescaled h' for next layer
                    hout[(size_t)node * 64 + jt * 16 + m] = __float2bfloat16(v);
                }
            }
        }
    }
}

// ---------- head (counts via binary search on sorted batch) ----------
__device__ inline int lower_bound_i(const int* __restrict__ a, int n, int key) {
    int lo = 0, hi = n;
    while (lo < hi) {
        int mid = (lo + hi) >> 1;
        if (a[mid] < key) lo = mid + 1; else hi = mid;
    }
    return lo;
}

__global__ void k_head(const float* __restrict__ sums, const int* __restrict__ batch,
                       const float* __restrict__ ge, const float* __restrict__ Wl,
                       const float* __restrict__ bl, float* __restrict__ out,
                       int n, int ng) {
    int g = blockIdx.x * blockDim.x + threadIdx.x;
    if (g < ng) {
        int lo = lower_bound_i(batch, n, g);
        int hi = lower_bound_i(batch, n, g + 1);
        float c = fmaxf((float)(hi - lo), 1.0f);
        float z[5];
        for (int cl = 0; cl < 5; cl++) z[cl] = bl[cl];
        for (int k = 0; k < 64; k++) {
            float p = sums[g * 64 + k] / c;
            for (int cl = 0; cl < 5; cl++) z[cl] += p * Wl[k * 5 + cl];
        }
        for (int k = 0; k < 64; k++) {
            float p = ge[g * 64 + k];
            for (int cl = 0; cl < 5; cl++) z[cl] += p * Wl[(64 + k) * 5 + cl];
        }
        float m = z[0];
        for (int cl = 1; cl < 5; cl++) m = fmaxf(m, z[cl]);
        float s = 0.0f;
        for (int cl = 0; cl < 5; cl++) s += expf(z[cl] - m);
        float lse = m + logf(s);
        for (int cl = 0; cl < 5; cl++) out[g * 5 + cl] = z[cl] - lse;
    }
}

#define ALIGN16(x) (((x) + 15) & ~(size_t)15)

extern "C" void kernel_launch(void* const* d_in, const int* in_sizes, int n_in,
                              void* d_out, int out_size, void* d_ws, size_t ws_size,
                              hipStream_t stream) {
    const float* x    = (const float*)d_in[0];
    const int*   ei   = (const int*)d_in[1];
    const int*   batch= (const int*)d_in[2];
    const float* ge   = (const float*)d_in[3];
    const float* W1   = (const float*)d_in[4];
    const float* b1   = (const float*)d_in[5];
    const float* W2   = (const float*)d_in[6];
    const float* b2   = (const float*)d_in[7];
    const float* W3   = (const float*)d_in[8];
    const float* b3   = (const float*)d_in[9];
    const float* Wl   = (const float*)d_in[10];
    const float* bl   = (const float*)d_in[11];
    float* out = (float*)d_out;

    const int N = in_sizes[0] / 2;   // x is [N,2]
    const int E = in_sizes[1] / 2;   // edge_index is [2,E]
    const int* src = ei;
    const int* dst = ei + E;
    const int NBUK = (N + 255) >> 8;             // actual dst buckets (<= NBIN)
    const int nbC  = (E + CHUNKB - 1) / CHUNKB;  // sort chunks

    // ---- workspace layout (segments 16B-aligned) ----
    char* wsb = (char*)d_ws;
    float* dinv   = (float*)wsb;                wsb += ALIGN16((size_t)N * 4);
    float2* xs    = (float2*)wsb;               wsb += ALIGN16((size_t)N * 8);   // x' = dinv*x
    __hip_bfloat16* h16 = (__hip_bfloat16*)wsb;  wsb += ALIGN16((size_t)64 * N * 2);  // h1'
    __hip_bfloat16* buf2= (__hip_bfloat16*)wsb;  wsb += ALIGN16((size_t)64 * N * 2);  // h2'
    float* sums   = (float*)wsb;                wsb += ALIGN16((size_t)NG * 64 * 4);
    __hip_bfloat16* Wf2 = (__hip_bfloat16*)wsb; wsb += ALIGN16((size_t)4096 * 2);
    __hip_bfloat16* Wf3 = (__hip_bfloat16*)wsb; wsb += ALIGN16((size_t)4096 * 2);
    int*   ebuck  = (int*)wsb;                  wsb += ALIGN16((size_t)E * 4);   // packed (ldst<<24|src)
    int*   csr    = (int*)wsb;                  wsb += ALIGN16((size_t)E * 4);   // src only
    int*   row_ptr= (int*)wsb;                  wsb += ALIGN16((size_t)(N + 1) * 4);
    int*   hist   = (int*)wsb;                  wsb += ALIGN16((size_t)NBIN * nbC * 4);
    int*   bsums  = (int*)wsb;                  wsb += 512 * 4;

    const int BS = 256;
    int gN   = (N + BS - 1) / BS;
    int gF   = (N + 15) / 16;                    // k_aggLin: 1 wave (16 nodes) per block
    int nH   = NBIN * nbC;
    int gH   = (nH + 511) / 512;                 // <= 512 for genscan2

    // ---- CSR build: single-pass bucket sort, all histograms in LDS ----
    k_bin_hist<<<nbC + 3, BS, 0, stream>>>(dst, hist, E, nbC, sums, W2, W3, Wf2, Wf3);
    genscan1<<<gH, 512, 0, stream>>>(hist, bsums, nH);
    genscan2<<<1, 512, 0, stream>>>(bsums, gH);
    k_bin_scatter<<<nbC, BS, 0, stream>>>(src, dst, hist, bsums, ebuck, E, nbC);
    k_csrAB<<<NBUK, BS, 0, stream>>>(ebuck, hist, bsums, x, row_ptr, dinv, xs, csr,
                                     N, nbC, E);

    // ---- layer 1: fused pull on x' + lin1 + relu -> h1' (h16) ----
    k_layer1<<<gN, BS, 0, stream>>>(row_ptr, csr, xs, dinv, W1, b1, h16, N);

    // ---- layer 2: fused agg(h1') + lin2 + relu -> h2' (buf2) ----
    k_aggLin<1, 0><<<gF, 64, 0, stream>>>(row_ptr, csr, h16, dinv, Wf2, b2, buf2,
                                          nullptr, nullptr, N);

    // ---- layer 3: fused agg(h2') + lin3 + mean-pool -> sums (no h3 buffer) ----
    k_aggLin<0, 1><<<gF, 64, 0, stream>>>(row_ptr, csr, buf2, dinv, Wf3, b3, nullptr,
                                          batch, sums, N);

    // ---- head ----
    k_head<<<1, 128, 0, stream>>>(sums, batch, ge, Wl, bl, out, N, NG);
}